// Round 2
// baseline (226.580 us; speedup 1.0000x reference)
//
#include <hip/hip_runtime.h>

typedef short v8s __attribute__((ext_vector_type(8)));
typedef float f32x4 __attribute__((ext_vector_type(4)));
typedef unsigned short ushort_t;

#define BB    8
#define CIN   512
#define COUT  512
#define SDIM  512

// async global->LDS DMA, 16B per lane (wave-uniform LDS base + lane*16)
#define GLDS(g, l)                                                      \
    __builtin_amdgcn_global_load_lds(                                   \
        (const __attribute__((address_space(1))) void*)(g),             \
        (__attribute__((address_space(3))) void*)(l), 16, 0, 0)

static __device__ __forceinline__ ushort_t f2bf(float f) {
    union { float f; unsigned u; } un; un.f = f;
    unsigned r = un.u + 0x7FFF + ((un.u >> 16) & 1);  // round-to-nearest-even
    return (ushort_t)(r >> 16);
}

// ---------------------------------------------------------------------------
// k_prep1: fused  (role by blockIdx)
//   blocks [0,1024):  q[o,c] = sum w^2 ; Wb phase-combined bf16 weights
//   blocks [1024,1040): m[b,c] = 1 + style[b,:] @ fc_w[c,:] + fc_b[c]
//   block 1024 also zeroes the 32B OOB guard used by k_gemm's DMA staging.
// ---------------------------------------------------------------------------
__global__ void k_prep1(const float* __restrict__ style, const float* __restrict__ fc_w,
                        const float* __restrict__ fc_b, float* __restrict__ m,
                        const float* __restrict__ conv_w, float* __restrict__ q,
                        ushort_t* __restrict__ Wb, float* __restrict__ guard) {
    __shared__ float sst[SDIM];
    const int bid = blockIdx.x;
    if (bid < 1024) {
        // ---- wprep role ----
        const int idx = bid * 256 + threadIdx.x;  // o*512 + c
        const int o = idx >> 9, c = idx & 511;
        float w[3][3];
        const float* wp = conv_w + idx * 9;
        float qs = 0.f;
        for (int i = 0; i < 3; i++)
            for (int j = 0; j < 3; j++) {
                float v = wp[i * 3 + j];
                w[i][j] = v;
                qs += v * v;
            }
        q[idx] = qs;
        const int ch = c >> 5, kg = (c >> 3) & 3, c8 = c & 7;
        for (int py = 0; py < 2; py++) {
            float rs[2][3];
            for (int kx = 0; kx < 3; kx++) {
                rs[0][kx] = (py == 0) ? w[0][kx] : w[0][kx] + w[1][kx];
                rs[1][kx] = (py == 0) ? w[1][kx] + w[2][kx] : w[2][kx];
            }
            for (int px = 0; px < 2; px++) {
                const int p = py * 2 + px;
                float vals[4];
                if (px == 0) {
                    vals[0] = rs[0][0];
                    vals[1] = rs[0][1] + rs[0][2];
                    vals[2] = rs[1][0];
                    vals[3] = rs[1][1] + rs[1][2];
                } else {
                    vals[0] = rs[0][0] + rs[0][1];
                    vals[1] = rs[0][2];
                    vals[2] = rs[1][0] + rs[1][1];
                    vals[3] = rs[1][2];
                }
                for (int t = 0; t < 4; t++)
                    Wb[(size_t)p * (16 * 4 * 4 * 512 * 8) + (size_t)ch * (4 * 4 * 512 * 8)
                       + ((size_t)(t * 4 + kg) * 512 + o) * 8 + c8] = f2bf(vals[t]);
            }
        }
    } else {
        // ---- style role ----
        const int sb = bid - 1024;
        const int bx = sb & 1, b = sb >> 1;
        if (sb == 0 && threadIdx.x < 8) guard[threadIdx.x] = 0.f;
        for (int k = threadIdx.x; k < SDIM; k += 256) sst[k] = style[b * SDIM + k];
        __syncthreads();
        const int c = bx * 256 + threadIdx.x;
        float acc = fc_b[c];
        const float* wr = fc_w + c * SDIM;
        for (int k = 0; k < SDIM; k += 4) {
            float4 w4 = *(const float4*)(wr + k);
            acc += w4.x * sst[k] + w4.y * sst[k + 1] + w4.z * sst[k + 2] + w4.w * sst[k + 3];
        }
        m[b * CIN + c] = acc + 1.0f;
    }
}

// ---------------------------------------------------------------------------
// k_prep2: fused  (role by blockIdx)
//   blocks [0,256):    Xt[b][r][q][c] = bf16( x[b][c][r][q] * m[b][c] )
//   blocks [256,1280): d[b,o] = rsqrt( sum_c m^2 q + 1e-8 ), one wave/(b,o)
// ---------------------------------------------------------------------------
__global__ void k_prep2(const float* __restrict__ x, const float* __restrict__ m,
                        ushort_t* __restrict__ Xt, const float* __restrict__ q,
                        float* __restrict__ d) {
    __shared__ __align__(16) ushort_t lt[32 * 528];  // [q][c], c-stride 528
    const int bid = blockIdx.x, t = threadIdx.x;
    if (bid < 256) {
        // ---- xprep role ----
        const int r = bid & 31, b = bid >> 5;
        for (int s = t; s < 4096; s += 256) {  // (c, q-quad)
            const int c = s >> 3, q4 = (s & 7) * 4;
            float4 v = *(const float4*)(x + (((size_t)(b * CIN + c) * 32 + r) * 32 + q4));
            const float mv = m[b * CIN + c];
            lt[(q4 + 0) * 528 + c] = f2bf(v.x * mv);
            lt[(q4 + 1) * 528 + c] = f2bf(v.y * mv);
            lt[(q4 + 2) * 528 + c] = f2bf(v.z * mv);
            lt[(q4 + 3) * 528 + c] = f2bf(v.w * mv);
        }
        __syncthreads();
        for (int s = t; s < 2048; s += 256) {  // (q, c-group of 8)
            const int qq = s >> 6, c8 = s & 63;
            v8s v = *(v8s*)&lt[qq * 528 + c8 * 8];
            *(v8s*)(Xt + (((size_t)(b * 32 + r) * 32 + qq) * 512 + c8 * 8)) = v;
        }
    } else {
        // ---- demod role ----
        const int w = (bid - 256) * 4 + (t >> 6);  // 0..4095
        const int L = t & 63;
        const int b = w >> 9, o = w & 511;
        float4 q1 = *(const float4*)(q + o * 512 + L * 8);
        float4 q2 = *(const float4*)(q + o * 512 + L * 8 + 4);
        float4 m1 = *(const float4*)(m + b * 512 + L * 8);
        float4 m2 = *(const float4*)(m + b * 512 + L * 8 + 4);
        float acc = m1.x * m1.x * q1.x + m1.y * m1.y * q1.y + m1.z * m1.z * q1.z +
                    m1.w * m1.w * q1.w + m2.x * m2.x * q2.x + m2.y * m2.y * q2.y +
                    m2.z * m2.z * q2.z + m2.w * m2.w * q2.w;
        for (int off = 32; off; off >>= 1) acc += __shfl_down(acc, off, 64);
        if (L == 0) d[w] = rsqrtf(acc + 1e-8f);
    }
}

// ---------------------------------------------------------------------------
// k_gemm v3: DMA staging (global_load_lds x16B) + linear LDS with XOR swizzle
// + 2-phase double buffer (BK=64: 16 ch x 4 taps) + bijective chunked XCD
// swizzle. Rationale: v2 was LDS-pipe-bound (~71% LDS busy: 3.1K cyc reads +
// 1.5K writes + 1K conflicts vs 2.5K MFMA per chunk/CU). DMA removes the
// ds_write half and VALU addressing; the XOR swizzle (T2, applied via
// pre-swizzled global source since the DMA writes linearly, m173) keeps
// reads ~2-way conflict (free). XCD chunking fits each XCD's working set
// (Wb_p 1MB + Xt_b 1MB) in its 4MB L2 (FETCH was 40MB vs 13MB unique).
// LDS = 2 buf x (16+16)KB = 64KB -> 2 blocks/CU.
// ---------------------------------------------------------------------------
__global__ __launch_bounds__(256, 2) void k_gemm(
    const ushort_t* __restrict__ Xt, const ushort_t* __restrict__ Wb,
    const float* __restrict__ dmod, const float* __restrict__ bias,
    const float* __restrict__ noise, float* __restrict__ out,
    const float* __restrict__ guard) {
    __shared__ __align__(16) ushort_t Wt[2][128 * 64];  // [o-local][k], swizzled
    __shared__ __align__(16) ushort_t Xs[2][128 * 64];  // [n-local][k], swizzled

    const int tid = threadIdx.x;
    const int L = tid & 63;
    const int wid = tid >> 6;

    // bijective chunked XCD swizzle: 1024 blocks, XCD k owns logical [k*128,(k+1)*128)
    const int lin = blockIdx.x + 4 * blockIdx.y + 32 * blockIdx.z;
    const int log = (lin & 7) * 128 + (lin >> 3);
    const int o0 = (log & 3) * 128;
    const int r0 = ((log >> 2) & 7) * 4;
    const int zz = log >> 5;
    const int b = zz >> 2, p = zz & 3;

    const int py = p >> 1, px = p & 1;
    const int ry0 = py ? 0 : -1, cx0 = px ? 0 : -1;
    const int wo = (wid >> 1) * 64, wn = (wid & 1) * 64;
    const int l15 = L & 15, l4 = L >> 4;

    const ushort_t* XtB = Xt + (size_t)b * (32 * 32 * 512);
    const ushort_t* WbP = Wb + (size_t)p * (16 * 4 * 4 * 512 * 8);

    f32x4 acc[4][4];
#pragma unroll
    for (int i = 0; i < 4; i++)
#pragma unroll
        for (int j = 0; j < 4; j++) acc[i][j] = {0.f, 0.f, 0.f, 0.f};

    // Stage one BK=64 chunk (channels c0..c0+15, 4 taps) into (wb,xb) via DMA.
    // LDS linear slot s (16B units): row = s>>3, stored k16 = (s&7) ^ (row&7).
    auto stage = [&](int c0, ushort_t* wbuf, ushort_t* xbuf) {
#pragma unroll
        for (int i = 0; i < 4; i++) {
            const int slot0 = i * 256 + (tid & 192);  // wave-uniform base slot
            const int slot = i * 256 + tid;
            const int row = slot >> 3;
            const int k16 = (slot & 7) ^ (row & 7);  // logical 16B k-group 0..7
            const int tp = k16 >> 1;                 // tap 0..3
            const int cg = c0 + (k16 & 1) * 8;       // global channel base of granule
            // W source: Wb[p][cg>>5][tp*4+kg][o0+row][0..7]
            const ushort_t* wsrc =
                WbP + (size_t)(cg >> 5) * (4 * 4 * 512 * 8)
                + ((size_t)((tp * 4 + ((cg >> 3) & 3)) * 512 + o0 + row)) * 8;
            GLDS(wsrc, wbuf + (size_t)slot0 * 8);
            // X source: pixel (gr,gq) for tap tp, channels cg..cg+7 (zero guard OOB)
            const int gr = r0 + (row >> 5) + ry0 + (tp >> 1);
            const int gq = (row & 31) + cx0 + (tp & 1);
            const ushort_t* xsrc =
                ((unsigned)gr < 32u && (unsigned)gq < 32u)
                    ? XtB + (size_t)((gr * 32 + gq) * 512 + cg)
                    : (const ushort_t*)guard;
            GLDS(xsrc, xbuf + (size_t)slot0 * 8);
        }
    };

    stage(0, Wt[0], Xs[0]);
    __syncthreads();  // drain DMA: buffer 0 ready

    const int swz = (l15 & 7) << 3;
    int cur = 0;
    for (int c0 = 0; c0 < CIN; c0 += 16) {
        if (c0 + 16 < CIN) stage(c0 + 16, Wt[cur ^ 1], Xs[cur ^ 1]);
        const ushort_t* wbuf = Wt[cur];
        const ushort_t* xbuf = Xs[cur];
#pragma unroll
        for (int s = 0; s < 2; s++) {
            const int ko = (s * 32 + l4 * 8) ^ swz;
            v8s af[4], bfr[4];
#pragma unroll
            for (int i = 0; i < 4; i++)
                af[i] = *(const v8s*)&wbuf[(wo + i * 16 + l15) * 64 + ko];
#pragma unroll
            for (int j = 0; j < 4; j++)
                bfr[j] = *(const v8s*)&xbuf[(wn + j * 16 + l15) * 64 + ko];
#pragma unroll
            for (int i = 0; i < 4; i++)
#pragma unroll
                for (int j = 0; j < 4; j++)
                    acc[i][j] = __builtin_amdgcn_mfma_f32_16x16x32_bf16(
                        af[i], bfr[j], acc[i][j], 0, 0, 0);
        }
        __syncthreads();  // next buffer's DMA drained; this buffer's reads done
        cur ^= 1;
    }

    // ---- epilogue: demod * acc + bias + noise, leaky relu ----
    const float* db = dmod + b * COUT;
    float nz[4];
    int ooff[4];
#pragma unroll
    for (int j = 0; j < 4; j++) {
        const int n = wn + j * 16 + l15;
        const int Y = 2 * (r0 + (n >> 5)) + py, X = 2 * (n & 31) + px;
        nz[j] = noise[b * 4096 + Y * 64 + X];
        ooff[j] = Y * 64 + X;
    }
    float* outB = out + (size_t)b * COUT * 4096;
#pragma unroll
    for (int i = 0; i < 4; i++) {
        const int ob = o0 + wo + i * 16 + l4 * 4;
        float4 d4 = *(const float4*)(db + ob);
        float4 b4 = *(const float4*)(bias + ob);
        const float dv[4] = {d4.x, d4.y, d4.z, d4.w};
        const float bv[4] = {b4.x, b4.y, b4.z, b4.w};
#pragma unroll
        for (int reg = 0; reg < 4; reg++) {
            float* orow = outB + (size_t)(ob + reg) * 4096;
#pragma unroll
            for (int j = 0; j < 4; j++) {
                float v = acc[i][j][reg] * dv[reg] + bv[reg] + nz[j];
                orow[ooff[j]] = v > 0.f ? v : 0.2f * v;
            }
        }
    }
}

// ---------------------------------------------------------------------------
extern "C" void kernel_launch(void* const* d_in, const int* in_sizes, int n_in,
                              void* d_out, int out_size, void* d_ws, size_t ws_size,
                              hipStream_t stream) {
    const float* x      = (const float*)d_in[0];
    const float* style  = (const float*)d_in[1];
    const float* noise  = (const float*)d_in[2];
    const float* conv_w = (const float*)d_in[3];
    const float* fc_w   = (const float*)d_in[4];
    const float* fc_b   = (const float*)d_in[5];
    const float* bias   = (const float*)d_in[6];
    float* out = (float*)d_out;

    float* ws = (float*)d_ws;
    float* m     = ws;             // 8*512 floats
    float* dmod  = ws + 4096;      // 8*512
    float* q     = ws + 8192;      // 512*512
    float* guard = ws + 270336;    // 8 floats (32B zero guard, 16B-aligned)
    ushort_t* XtU = (ushort_t*)(ws + 270352);  // 8*32*32*512 bf16
    ushort_t* WbU = XtU + 4194304;             // 4*16*4*4*512*8 bf16

    k_prep1<<<1040, 256, 0, stream>>>(style, fc_w, fc_b, m, conv_w, q, WbU, guard);
    k_prep2<<<1280, 256, 0, stream>>>(x, m, XtU, q, dmod);
    k_gemm<<<dim3(4, 8, 32), 256, 0, stream>>>(XtU, WbU, dmod, bias, noise, out, guard);
}

// Round 3
// 216.277 us; speedup vs baseline: 1.0476x; 1.0476x over previous
//
#include <hip/hip_runtime.h>

typedef short v8s __attribute__((ext_vector_type(8)));
typedef float f32x4 __attribute__((ext_vector_type(4)));
typedef float f32x16 __attribute__((ext_vector_type(16)));
typedef unsigned short ushort_t;

#define BB    8
#define CIN   512
#define COUT  512
#define SDIM  512

// async global->LDS DMA, 16B per lane (wave-uniform LDS base + lane*16)
#define GLDS(g, l)                                                      \
    __builtin_amdgcn_global_load_lds(                                   \
        (const __attribute__((address_space(1))) void*)(g),             \
        (__attribute__((address_space(3))) void*)(l), 16, 0, 0)

static __device__ __forceinline__ ushort_t f2bf(float f) {
    union { float f; unsigned u; } un; un.f = f;
    unsigned r = un.u + 0x7FFF + ((un.u >> 16) & 1);  // round-to-nearest-even
    return (ushort_t)(r >> 16);
}

// ---------------------------------------------------------------------------
// k_prep1: fused  (role by blockIdx)
//   blocks [0,1024):  q[o,c] = sum w^2 ; Wb phase-combined bf16 weights
//   blocks [1024,1040): m[b,c] = 1 + style[b,:] @ fc_w[c,:] + fc_b[c]
//   block 1024 also zeroes the 32B OOB guard used by k_gemm's DMA staging.
// ---------------------------------------------------------------------------
__global__ void k_prep1(const float* __restrict__ style, const float* __restrict__ fc_w,
                        const float* __restrict__ fc_b, float* __restrict__ m,
                        const float* __restrict__ conv_w, float* __restrict__ q,
                        ushort_t* __restrict__ Wb, float* __restrict__ guard) {
    __shared__ float sst[SDIM];
    const int bid = blockIdx.x;
    if (bid < 1024) {
        // ---- wprep role ----
        const int idx = bid * 256 + threadIdx.x;  // o*512 + c
        const int o = idx >> 9, c = idx & 511;
        float w[3][3];
        const float* wp = conv_w + idx * 9;
        float qs = 0.f;
        for (int i = 0; i < 3; i++)
            for (int j = 0; j < 3; j++) {
                float v = wp[i * 3 + j];
                w[i][j] = v;
                qs += v * v;
            }
        q[idx] = qs;
        const int ch = c >> 5, kg = (c >> 3) & 3, c8 = c & 7;
        for (int py = 0; py < 2; py++) {
            float rs[2][3];
            for (int kx = 0; kx < 3; kx++) {
                rs[0][kx] = (py == 0) ? w[0][kx] : w[0][kx] + w[1][kx];
                rs[1][kx] = (py == 0) ? w[1][kx] + w[2][kx] : w[2][kx];
            }
            for (int px = 0; px < 2; px++) {
                const int p = py * 2 + px;
                float vals[4];
                if (px == 0) {
                    vals[0] = rs[0][0];
                    vals[1] = rs[0][1] + rs[0][2];
                    vals[2] = rs[1][0];
                    vals[3] = rs[1][1] + rs[1][2];
                } else {
                    vals[0] = rs[0][0] + rs[0][1];
                    vals[1] = rs[0][2];
                    vals[2] = rs[1][0] + rs[1][1];
                    vals[3] = rs[1][2];
                }
                for (int t = 0; t < 4; t++)
                    Wb[(size_t)p * (16 * 4 * 4 * 512 * 8) + (size_t)ch * (4 * 4 * 512 * 8)
                       + ((size_t)(t * 4 + kg) * 512 + o) * 8 + c8] = f2bf(vals[t]);
            }
        }
    } else {
        // ---- style role ----
        const int sb = bid - 1024;
        const int bx = sb & 1, b = sb >> 1;
        if (sb == 0 && threadIdx.x < 8) guard[threadIdx.x] = 0.f;
        for (int k = threadIdx.x; k < SDIM; k += 256) sst[k] = style[b * SDIM + k];
        __syncthreads();
        const int c = bx * 256 + threadIdx.x;
        float acc = fc_b[c];
        const float* wr = fc_w + c * SDIM;
        for (int k = 0; k < SDIM; k += 4) {
            float4 w4 = *(const float4*)(wr + k);
            acc += w4.x * sst[k] + w4.y * sst[k + 1] + w4.z * sst[k + 2] + w4.w * sst[k + 3];
        }
        m[b * CIN + c] = acc + 1.0f;
    }
}

// ---------------------------------------------------------------------------
// k_prep2: fused  (role by blockIdx)
//   blocks [0,256):    Xt[b][r][q][c] = bf16( x[b][c][r][q] * m[b][c] )
//   blocks [256,1280): d[b,o] = rsqrt( sum_c m^2 q + 1e-8 ), one wave/(b,o)
// ---------------------------------------------------------------------------
__global__ void k_prep2(const float* __restrict__ x, const float* __restrict__ m,
                        ushort_t* __restrict__ Xt, const float* __restrict__ q,
                        float* __restrict__ d) {
    __shared__ __align__(16) ushort_t lt[32 * 528];  // [q][c], c-stride 528
    const int bid = blockIdx.x, t = threadIdx.x;
    if (bid < 256) {
        // ---- xprep role ----
        const int r = bid & 31, b = bid >> 5;
        for (int s = t; s < 4096; s += 256) {  // (c, q-quad)
            const int c = s >> 3, q4 = (s & 7) * 4;
            float4 v = *(const float4*)(x + (((size_t)(b * CIN + c) * 32 + r) * 32 + q4));
            const float mv = m[b * CIN + c];
            lt[(q4 + 0) * 528 + c] = f2bf(v.x * mv);
            lt[(q4 + 1) * 528 + c] = f2bf(v.y * mv);
            lt[(q4 + 2) * 528 + c] = f2bf(v.z * mv);
            lt[(q4 + 3) * 528 + c] = f2bf(v.w * mv);
        }
        __syncthreads();
        for (int s = t; s < 2048; s += 256) {  // (q, c-group of 8)
            const int qq = s >> 6, c8 = s & 63;
            v8s v = *(v8s*)&lt[qq * 528 + c8 * 8];
            *(v8s*)(Xt + (((size_t)(b * 32 + r) * 32 + qq) * 512 + c8 * 8)) = v;
        }
    } else {
        // ---- demod role ----
        const int w = (bid - 256) * 4 + (t >> 6);  // 0..4095
        const int L = t & 63;
        const int b = w >> 9, o = w & 511;
        float4 q1 = *(const float4*)(q + o * 512 + L * 8);
        float4 q2 = *(const float4*)(q + o * 512 + L * 8 + 4);
        float4 m1 = *(const float4*)(m + b * 512 + L * 8);
        float4 m2 = *(const float4*)(m + b * 512 + L * 8 + 4);
        float acc = m1.x * m1.x * q1.x + m1.y * m1.y * q1.y + m1.z * m1.z * q1.z +
                    m1.w * m1.w * q1.w + m2.x * m2.x * q2.x + m2.y * m2.y * q2.y +
                    m2.z * m2.z * q2.z + m2.w * m2.w * q2.w;
        for (int off = 32; off; off >>= 1) acc += __shfl_down(acc, off, 64);
        if (L == 0) d[w] = rsqrtf(acc + 1e-8f);
    }
}

// ---------------------------------------------------------------------------
// k_gemm v4: m201-style 256x256 block tile, 8 waves (512 thr) of 128x64,
// mfma_f32_32x32x16_bf16 (acc 4x2 of f32x16), BK=64, double-buffered LDS
// (128 KiB), DMA staging with pre-swizzled source, 4-phase schedule:
//   {6 ds_read (one k16-step) | 4 GLDS prefetch} barrier setprio(1)
//   8 MFMA setprio(0) barrier       -- vmcnt(0) only at phase 3 (drain ~free)
// Rationale: v3 was stall-bound (64% dead time; both pipes <40%). 128x64
// wave tiles raise FLOP/LDS-byte 32->42.7 (LDS floor ~31us ~ MFMA floor
// 27.5us); the per-phase barrier schedule lets MFMA execution overlap the
// next phase's ds_reads (waitcnt-free barriers), the proven T3+T4 lever.
// Grid = 2x4x32 = 256 blocks = exactly 1/CU.
// ---------------------------------------------------------------------------
__global__ __launch_bounds__(512, 2) void k_gemm(
    const ushort_t* __restrict__ Xt, const ushort_t* __restrict__ Wb,
    const float* __restrict__ dmod, const float* __restrict__ bias,
    const float* __restrict__ noise, float* __restrict__ out,
    const float* __restrict__ guard) {
    __shared__ __align__(16) ushort_t Wt[2][256 * 64];  // [o-local][k], swizzled
    __shared__ __align__(16) ushort_t Xs[2][256 * 64];  // [n-local][k], swizzled

    const int tid = threadIdx.x;
    const int L = tid & 63;
    const int wid = tid >> 6;

    // bijective chunked XCD swizzle: 256 blocks, XCD k owns logical [k*32,(k+1)*32)
    const int lin = blockIdx.x + 2 * blockIdx.y + 8 * blockIdx.z;
    const int log = (lin & 7) * 32 + (lin >> 3);
    const int o0 = (log & 1) * 256;
    const int n0 = ((log >> 1) & 3) * 256;
    const int zz = log >> 3;
    const int b = zz >> 2, p = zz & 3;

    const int py = p >> 1, px = p & 1;
    const int ry0 = py ? 0 : -1, cx0 = px ? 0 : -1;
    const int wo = (wid >> 2) * 128, wn = (wid & 3) * 64;
    const int l31 = L & 31, h = L >> 5;

    const ushort_t* XtB = Xt + (size_t)b * (32 * 32 * 512);
    const ushort_t* WbP = Wb + (size_t)p * (16 * 4 * 4 * 512 * 8);

    f32x16 acc[4][2];
#pragma unroll
    for (int i = 0; i < 4; i++)
#pragma unroll
        for (int j = 0; j < 2; j++)
#pragma unroll
            for (int r = 0; r < 16; r++) acc[i][j][r] = 0.f;

    // ---- staging (v3-verbatim index math; 256 rows, 8 granules of 16B) ----
    // LDS slot s: row = s>>3, stored granule gs = s&7; logical g = gs^(row&7)
    // g -> (tap = g>>1, ch8 = c0 + (g&1)*8)
    auto stage_w = [&](int c0, ushort_t* wbuf) {
#pragma unroll
        for (int i = 0; i < 4; i++) {
            const int slot = i * 512 + tid;
            const int row = slot >> 3;
            const int g = (slot & 7) ^ (row & 7);
            const int tap = g >> 1;
            const int cg = c0 + (g & 1) * 8;
            const ushort_t* wsrc =
                WbP + (size_t)(cg >> 5) * (4 * 4 * 512 * 8)
                + ((size_t)((tap * 4 + ((cg >> 3) & 3)) * 512 + o0 + row)) * 8;
            GLDS(wsrc, wbuf + (size_t)(i * 512 + (tid & 448)) * 8);
        }
    };
    auto stage_x = [&](int c0, ushort_t* xbuf) {
#pragma unroll
        for (int i = 0; i < 4; i++) {
            const int slot = i * 512 + tid;
            const int row = slot >> 3;
            const int g = (slot & 7) ^ (row & 7);
            const int tap = g >> 1;
            const int cg = c0 + (g & 1) * 8;
            const int pix = n0 + row;
            const int gr = (pix >> 5) + ry0 + (tap >> 1);
            const int gq = (pix & 31) + cx0 + (tap & 1);
            const ushort_t* xsrc =
                ((unsigned)gr < 32u && (unsigned)gq < 32u)
                    ? XtB + (size_t)((gr * 32 + gq) * 512 + cg)
                    : (const ushort_t*)guard;
            GLDS(xsrc, xbuf + (size_t)(i * 512 + (tid & 448)) * 8);
        }
    };

    stage_w(0, Wt[0]);
    stage_x(0, Xs[0]);
    asm volatile("s_waitcnt vmcnt(0)" ::: "memory");
    __syncthreads();

    int cur = 0;
    for (int t = 0; t < 32; ++t) {
        const ushort_t* wb = Wt[cur];
        const ushort_t* xb = Xs[cur];
        const int c0n = (t + 1) * 16;
#pragma unroll
        for (int s = 0; s < 4; ++s) {
            // ds_read one k16-step: granule = 2s + h, swizzled by row&7 (=L&7)
            v8s af[4], bfr[2];
            const int ga = (2 * s + h) ^ (l31 & 7);
#pragma unroll
            for (int i = 0; i < 4; i++) {
                const int row = wo + i * 32 + l31;
                af[i] = *(const v8s*)&wb[row * 64 + ga * 8];
            }
#pragma unroll
            for (int j = 0; j < 2; j++) {
                const int row = wn + j * 32 + l31;
                bfr[j] = *(const v8s*)&xb[row * 64 + ga * 8];
            }
            // prefetch next K-tile: W in phase 0, X in phase 1
            if (t < 31) {
                if (s == 0) stage_w(c0n, Wt[cur ^ 1]);
                else if (s == 1) stage_x(c0n, Xs[cur ^ 1]);
            }
            __builtin_amdgcn_s_barrier();
            __builtin_amdgcn_s_setprio(1);
#pragma unroll
            for (int i = 0; i < 4; i++)
#pragma unroll
                for (int j = 0; j < 2; j++)
                    acc[i][j] = __builtin_amdgcn_mfma_f32_32x32x16_bf16(
                        af[i], bfr[j], acc[i][j], 0, 0, 0);
            __builtin_amdgcn_s_setprio(0);
            if (s == 3) asm volatile("s_waitcnt vmcnt(0)" ::: "memory");
            __builtin_amdgcn_s_barrier();
        }
        cur ^= 1;
    }

    // ---- epilogue: demod * acc + bias + noise, leaky relu ----
    // 32x32 C/D map: col = lane&31, row = (reg&3) + 8*(reg>>2) + 4*(lane>>5)
    const float* db = dmod + b * COUT;
    float nz[2];
    int ooff[2];
#pragma unroll
    for (int j = 0; j < 2; j++) {
        const int pix = n0 + wn + j * 32 + l31;
        const int Y = 2 * (pix >> 5) + py, X = 2 * (pix & 31) + px;
        nz[j] = noise[b * 4096 + Y * 64 + X];
        ooff[j] = Y * 64 + X;
    }
    float* outB = out + (size_t)b * COUT * 4096;
#pragma unroll
    for (int i = 0; i < 4; i++) {
#pragma unroll
        for (int rq = 0; rq < 4; rq++) {
            const int ob = o0 + wo + i * 32 + rq * 8 + h * 4;
            float4 d4 = *(const float4*)(db + ob);
            float4 b4 = *(const float4*)(bias + ob);
            const float dv[4] = {d4.x, d4.y, d4.z, d4.w};
            const float bv[4] = {b4.x, b4.y, b4.z, b4.w};
#pragma unroll
            for (int rr = 0; rr < 4; rr++) {
                const int reg = rq * 4 + rr;
                float* orow = outB + (size_t)(ob + rr) * 4096;
#pragma unroll
                for (int j = 0; j < 2; j++) {
                    float v = acc[i][j][reg] * dv[rr] + bv[rr] + nz[j];
                    orow[ooff[j]] = v > 0.f ? v : 0.2f * v;
                }
            }
        }
    }
}

// ---------------------------------------------------------------------------
extern "C" void kernel_launch(void* const* d_in, const int* in_sizes, int n_in,
                              void* d_out, int out_size, void* d_ws, size_t ws_size,
                              hipStream_t stream) {
    const float* x      = (const float*)d_in[0];
    const float* style  = (const float*)d_in[1];
    const float* noise  = (const float*)d_in[2];
    const float* conv_w = (const float*)d_in[3];
    const float* fc_w   = (const float*)d_in[4];
    const float* fc_b   = (const float*)d_in[5];
    const float* bias   = (const float*)d_in[6];
    float* out = (float*)d_out;

    float* ws = (float*)d_ws;
    float* m     = ws;             // 8*512 floats
    float* dmod  = ws + 4096;      // 8*512
    float* q     = ws + 8192;      // 512*512
    float* guard = ws + 270336;    // 8 floats (32B zero guard, 16B-aligned)
    ushort_t* XtU = (ushort_t*)(ws + 270352);  // 8*32*32*512 bf16
    ushort_t* WbU = XtU + 4194304;             // 4*16*4*4*512*8 bf16

    k_prep1<<<1040, 256, 0, stream>>>(style, fc_w, fc_b, m, conv_w, q, WbU, guard);
    k_prep2<<<1280, 256, 0, stream>>>(x, m, XtU, q, dmod);
    k_gemm<<<dim3(2, 4, 32), 512, 0, stream>>>(XtU, WbU, dmod, bias, noise, out, guard);
}

// Round 4
// 201.980 us; speedup vs baseline: 1.1218x; 1.0708x over previous
//
#include <hip/hip_runtime.h>

typedef short v8s __attribute__((ext_vector_type(8)));
typedef float f32x4 __attribute__((ext_vector_type(4)));
typedef unsigned short ushort_t;

#define BB    8
#define CIN   512
#define COUT  512
#define SDIM  512

// async global->LDS DMA, 16B per lane (wave-uniform LDS base + lane*16)
#define GLDS(g, l)                                                      \
    __builtin_amdgcn_global_load_lds(                                   \
        (const __attribute__((address_space(1))) void*)(g),             \
        (__attribute__((address_space(3))) void*)(l), 16, 0, 0)

static __device__ __forceinline__ ushort_t f2bf(float f) {
    union { float f; unsigned u; } un; un.f = f;
    unsigned r = un.u + 0x7FFF + ((un.u >> 16) & 1);  // round-to-nearest-even
    return (ushort_t)(r >> 16);
}

// ---------------------------------------------------------------------------
// k_prep1: fused  (role by blockIdx)
//   blocks [0,1024):  q[o,c] = sum w^2 ; Wb phase-combined bf16 weights
//   blocks [1024,1040): m[b,c] = 1 + style[b,:] @ fc_w[c,:] + fc_b[c]
//   block 1024 also zeroes the 32B OOB guard used by k_gemm's DMA staging.
// ---------------------------------------------------------------------------
__global__ void k_prep1(const float* __restrict__ style, const float* __restrict__ fc_w,
                        const float* __restrict__ fc_b, float* __restrict__ m,
                        const float* __restrict__ conv_w, float* __restrict__ q,
                        ushort_t* __restrict__ Wb, float* __restrict__ guard) {
    __shared__ float sst[SDIM];
    const int bid = blockIdx.x;
    if (bid < 1024) {
        // ---- wprep role ----
        const int idx = bid * 256 + threadIdx.x;  // o*512 + c
        const int o = idx >> 9, c = idx & 511;
        float w[3][3];
        const float* wp = conv_w + idx * 9;
        float qs = 0.f;
        for (int i = 0; i < 3; i++)
            for (int j = 0; j < 3; j++) {
                float v = wp[i * 3 + j];
                w[i][j] = v;
                qs += v * v;
            }
        q[idx] = qs;
        const int ch = c >> 5, kg = (c >> 3) & 3, c8 = c & 7;
        for (int py = 0; py < 2; py++) {
            float rs[2][3];
            for (int kx = 0; kx < 3; kx++) {
                rs[0][kx] = (py == 0) ? w[0][kx] : w[0][kx] + w[1][kx];
                rs[1][kx] = (py == 0) ? w[1][kx] + w[2][kx] : w[2][kx];
            }
            for (int px = 0; px < 2; px++) {
                const int p = py * 2 + px;
                float vals[4];
                if (px == 0) {
                    vals[0] = rs[0][0];
                    vals[1] = rs[0][1] + rs[0][2];
                    vals[2] = rs[1][0];
                    vals[3] = rs[1][1] + rs[1][2];
                } else {
                    vals[0] = rs[0][0] + rs[0][1];
                    vals[1] = rs[0][2];
                    vals[2] = rs[1][0] + rs[1][1];
                    vals[3] = rs[1][2];
                }
                for (int t = 0; t < 4; t++)
                    Wb[(size_t)p * (16 * 4 * 4 * 512 * 8) + (size_t)ch * (4 * 4 * 512 * 8)
                       + ((size_t)(t * 4 + kg) * 512 + o) * 8 + c8] = f2bf(vals[t]);
            }
        }
    } else {
        // ---- style role ----
        const int sb = bid - 1024;
        const int bx = sb & 1, b = sb >> 1;
        if (sb == 0 && threadIdx.x < 8) guard[threadIdx.x] = 0.f;
        for (int k = threadIdx.x; k < SDIM; k += 256) sst[k] = style[b * SDIM + k];
        __syncthreads();
        const int c = bx * 256 + threadIdx.x;
        float acc = fc_b[c];
        const float* wr = fc_w + c * SDIM;
        for (int k = 0; k < SDIM; k += 4) {
            float4 w4 = *(const float4*)(wr + k);
            acc += w4.x * sst[k] + w4.y * sst[k + 1] + w4.z * sst[k + 2] + w4.w * sst[k + 3];
        }
        m[b * CIN + c] = acc + 1.0f;
    }
}

// ---------------------------------------------------------------------------
// k_prep2: fused  (role by blockIdx)
//   blocks [0,256):    Xt[b][r][q][c] = bf16( x[b][c][r][q] * m[b][c] )
//   blocks [256,1280): d[b,o] = rsqrt( sum_c m^2 q + 1e-8 ), one wave/(b,o)
// ---------------------------------------------------------------------------
__global__ void k_prep2(const float* __restrict__ x, const float* __restrict__ m,
                        ushort_t* __restrict__ Xt, const float* __restrict__ q,
                        float* __restrict__ d) {
    __shared__ __align__(16) ushort_t lt[32 * 528];  // [q][c], c-stride 528
    const int bid = blockIdx.x, t = threadIdx.x;
    if (bid < 256) {
        // ---- xprep role ----
        const int r = bid & 31, b = bid >> 5;
        for (int s = t; s < 4096; s += 256) {  // (c, q-quad)
            const int c = s >> 3, q4 = (s & 7) * 4;
            float4 v = *(const float4*)(x + (((size_t)(b * CIN + c) * 32 + r) * 32 + q4));
            const float mv = m[b * CIN + c];
            lt[(q4 + 0) * 528 + c] = f2bf(v.x * mv);
            lt[(q4 + 1) * 528 + c] = f2bf(v.y * mv);
            lt[(q4 + 2) * 528 + c] = f2bf(v.z * mv);
            lt[(q4 + 3) * 528 + c] = f2bf(v.w * mv);
        }
        __syncthreads();
        for (int s = t; s < 2048; s += 256) {  // (q, c-group of 8)
            const int qq = s >> 6, c8 = s & 63;
            v8s v = *(v8s*)&lt[qq * 528 + c8 * 8];
            *(v8s*)(Xt + (((size_t)(b * 32 + r) * 32 + qq) * 512 + c8 * 8)) = v;
        }
    } else {
        // ---- demod role ----
        const int w = (bid - 256) * 4 + (t >> 6);  // 0..4095
        const int L = t & 63;
        const int b = w >> 9, o = w & 511;
        float4 q1 = *(const float4*)(q + o * 512 + L * 8);
        float4 q2 = *(const float4*)(q + o * 512 + L * 8 + 4);
        float4 m1 = *(const float4*)(m + b * 512 + L * 8);
        float4 m2 = *(const float4*)(m + b * 512 + L * 8 + 4);
        float acc = m1.x * m1.x * q1.x + m1.y * m1.y * q1.y + m1.z * m1.z * q1.z +
                    m1.w * m1.w * q1.w + m2.x * m2.x * q2.x + m2.y * m2.y * q2.y +
                    m2.z * m2.z * q2.z + m2.w * m2.w * q2.w;
        for (int off = 32; off; off >>= 1) acc += __shfl_down(acc, off, 64);
        if (L == 0) d[w] = rsqrtf(acc + 1e-8f);
    }
}

// ---------------------------------------------------------------------------
// k_gemm v5: faithful m201-template port. 256x256 block tile, 8 waves of
// 128x64, 16x16x32 MFMA (acc[8][4], v3-verified mapping), BK=32 (8ch x 4taps),
// 4-deep K-tile ring (4 x 32KB = 128KB LDS). During tile t stage tile t+3
// (2 GLDS ops/phase); counted vmcnt(8) ONCE per tile (never 0 until the
// tail taper 8->4->0). Phase = {8|4 ds_read + 2 GLDS -> barrier ->
// lgkmcnt(0)+sched_barrier -> setprio(1) 16 MFMA setprio(0) -> barrier}.
// Swizzle: stored granule = tap ^ ((row>>1)&3); read pattern is v3's
// (l15-rows), which measured ZERO bank conflicts (v4's l31-row pattern
// was a 4-way conflict = 6.29M cycles).
// ---------------------------------------------------------------------------
__global__ __launch_bounds__(512, 2) void k_gemm(
    const ushort_t* __restrict__ Xt, const ushort_t* __restrict__ Wb,
    const float* __restrict__ dmod, const float* __restrict__ bias,
    const float* __restrict__ noise, float* __restrict__ out,
    const float* __restrict__ guard) {
    __shared__ __align__(16) ushort_t Wt[4][256 * 32];  // [o-local][k], swizzled
    __shared__ __align__(16) ushort_t Xs[4][256 * 32];  // [n-local][k], swizzled

    const int tid = threadIdx.x;
    const int L = tid & 63;
    const int wid = tid >> 6;

    // bijective chunked XCD swizzle: 256 blocks, XCD k owns logical [k*32,(k+1)*32)
    const int lin = blockIdx.x + 2 * blockIdx.y + 8 * blockIdx.z;
    const int log = (lin & 7) * 32 + (lin >> 3);
    const int o0 = (log & 1) * 256;
    const int n0 = ((log >> 1) & 3) * 256;
    const int zz = log >> 3;
    const int b = zz >> 2, p = zz & 3;

    const int py = p >> 1, px = p & 1;
    const int ry0 = py ? 0 : -1, cx0 = px ? 0 : -1;
    const int wo = (wid >> 2) * 128, wn = (wid & 3) * 64;
    const int l15 = L & 15, l4 = L >> 4;

    const ushort_t* XtB = Xt + (size_t)b * (32 * 32 * 512);
    const ushort_t* WbP = Wb + (size_t)p * (16 * 4 * 4 * 512 * 8);

    f32x4 acc[8][4];
#pragma unroll
    for (int i = 0; i < 8; i++)
#pragma unroll
        for (int j = 0; j < 4; j++) acc[i][j] = {0.f, 0.f, 0.f, 0.f};

    // ---- staging: one op = 512 lanes x 16B = 8KB = half a 16KB tile ----
    // LDS slot s (16B units): row = s>>2, stored granule gs = s&3,
    // logical tap = gs ^ ((row>>1)&3). Channels c0..c0+7 (BK=32).
    auto stage1 = [&](int c0, ushort_t* wbuf, ushort_t* xbuf, int i) {
        const int slot = i * 512 + tid;
        const int row = slot >> 2;
        const int tap = (slot & 3) ^ ((row >> 1) & 3);
        const int ldo = (i * 512 + (tid & 448)) * 8;  // wave-uniform base
        const ushort_t* wsrc =
            WbP + (size_t)(c0 >> 5) * (4 * 4 * 512 * 8)
            + ((size_t)((tap * 4 + ((c0 >> 3) & 3)) * 512 + o0 + row)) * 8;
        GLDS(wsrc, wbuf + ldo);
        const int pix = n0 + row;
        const int gr = (pix >> 5) + ry0 + (tap >> 1);
        const int gq = (pix & 31) + cx0 + (tap & 1);
        const ushort_t* xsrc =
            ((unsigned)gr < 32u && (unsigned)gq < 32u)
                ? XtB + (size_t)((gr * 32 + gq) * 512 + c0)
                : (const ushort_t*)guard;
        GLDS(xsrc, xbuf + ldo);
    };

    // fragment read: row in [0,256), k-granule l4, swizzled
    auto lread = [&](const ushort_t* buf, int row) -> v8s {
        const int gsel = l4 ^ ((row >> 1) & 3);
        return *(const v8s*)&buf[row * 32 + gsel * 8];
    };

    // ---- prologue: stage tiles 0,1,2 (12 ops); wait tile0 (vmcnt(8)) ----
#pragma unroll
    for (int pt = 0; pt < 3; ++pt) {
        stage1(pt * 8, Wt[pt], Xs[pt], 0);
        stage1(pt * 8, Wt[pt], Xs[pt], 1);
    }
    asm volatile("s_waitcnt vmcnt(8)" ::: "memory");
    __builtin_amdgcn_s_barrier();

    v8s bfr[4];
    for (int t = 0; t < 64; ++t) {
        const ushort_t* wb = Wt[t & 3];
        const ushort_t* xb = Xs[t & 3];
        ushort_t* wnb = Wt[(t + 3) & 3];
        ushort_t* xnb = Xs[(t + 3) & 3];
        const int c0n = (t + 3) * 8;
        const bool st = (t + 3) < 64;

        // ---- phase 0: quadrant 0 (rows wo..wo+63) ----
        {
            v8s af[4];
#pragma unroll
            for (int i = 0; i < 4; i++) af[i] = lread(wb, wo + i * 16 + l15);
#pragma unroll
            for (int j = 0; j < 4; j++) bfr[j] = lread(xb, wn + j * 16 + l15);
            if (st) stage1(c0n, wnb, xnb, 0);
            __builtin_amdgcn_s_barrier();
            asm volatile("s_waitcnt lgkmcnt(0)" ::: "memory");
            __builtin_amdgcn_sched_barrier(0);
            __builtin_amdgcn_s_setprio(1);
#pragma unroll
            for (int i = 0; i < 4; i++)
#pragma unroll
                for (int j = 0; j < 4; j++)
                    acc[i][j] = __builtin_amdgcn_mfma_f32_16x16x32_bf16(
                        af[i], bfr[j], acc[i][j], 0, 0, 0);
            __builtin_amdgcn_s_setprio(0);
            __builtin_amdgcn_s_barrier();
        }
        // ---- phase 1: quadrant 1 (rows wo+64..wo+127), reuse bfr ----
        {
            v8s af[4];
#pragma unroll
            for (int i = 0; i < 4; i++) af[i] = lread(wb, wo + 64 + i * 16 + l15);
            if (st) stage1(c0n, wnb, xnb, 1);
            __builtin_amdgcn_s_barrier();
            asm volatile("s_waitcnt lgkmcnt(0)" ::: "memory");
            __builtin_amdgcn_sched_barrier(0);
            __builtin_amdgcn_s_setprio(1);
#pragma unroll
            for (int i = 0; i < 4; i++)
#pragma unroll
                for (int j = 0; j < 4; j++)
                    acc[4 + i][j] = __builtin_amdgcn_mfma_f32_16x16x32_bf16(
                        af[i], bfr[j], acc[4 + i][j], 0, 0, 0);
            __builtin_amdgcn_s_setprio(0);
            // counted vmcnt, once per K-tile: wait only tile t+1's 4 ops;
            // keep the 8 newest (t+2, t+3) in flight. Taper at the tail.
            if (t <= 60) asm volatile("s_waitcnt vmcnt(8)" ::: "memory");
            else if (t == 61) asm volatile("s_waitcnt vmcnt(4)" ::: "memory");
            else if (t == 62) asm volatile("s_waitcnt vmcnt(0)" ::: "memory");
            __builtin_amdgcn_s_barrier();
        }
    }

    // ---- epilogue: demod * acc + bias + noise, leaky relu (v3-verified) ----
    const float* db = dmod + b * COUT;
    float nz[4];
    int ooff[4];
#pragma unroll
    for (int j = 0; j < 4; j++) {
        const int pix = n0 + wn + j * 16 + l15;
        const int Y = 2 * (pix >> 5) + py, X = 2 * (pix & 31) + px;
        nz[j] = noise[b * 4096 + Y * 64 + X];
        ooff[j] = Y * 64 + X;
    }
    float* outB = out + (size_t)b * COUT * 4096;
#pragma unroll
    for (int i = 0; i < 8; i++) {
        const int ob = o0 + wo + i * 16 + l4 * 4;
        float4 d4 = *(const float4*)(db + ob);
        float4 b4 = *(const float4*)(bias + ob);
        const float dv[4] = {d4.x, d4.y, d4.z, d4.w};
        const float bv[4] = {b4.x, b4.y, b4.z, b4.w};
#pragma unroll
        for (int reg = 0; reg < 4; reg++) {
            float* orow = outB + (size_t)(ob + reg) * 4096;
#pragma unroll
            for (int j = 0; j < 4; j++) {
                float v = acc[i][j][reg] * dv[reg] + bv[reg] + nz[j];
                orow[ooff[j]] = v > 0.f ? v : 0.2f * v;
            }
        }
    }
}

// ---------------------------------------------------------------------------
extern "C" void kernel_launch(void* const* d_in, const int* in_sizes, int n_in,
                              void* d_out, int out_size, void* d_ws, size_t ws_size,
                              hipStream_t stream) {
    const float* x      = (const float*)d_in[0];
    const float* style  = (const float*)d_in[1];
    const float* noise  = (const float*)d_in[2];
    const float* conv_w = (const float*)d_in[3];
    const float* fc_w   = (const float*)d_in[4];
    const float* fc_b   = (const float*)d_in[5];
    const float* bias   = (const float*)d_in[6];
    float* out = (float*)d_out;

    float* ws = (float*)d_ws;
    float* m     = ws;             // 8*512 floats
    float* dmod  = ws + 4096;      // 8*512
    float* q     = ws + 8192;      // 512*512
    float* guard = ws + 270336;    // 8 floats (32B zero guard, 16B-aligned)
    ushort_t* XtU = (ushort_t*)(ws + 270352);  // 8*32*32*512 bf16
    ushort_t* WbU = XtU + 4194304;             // 4*16*4*4*512*8 bf16

    k_prep1<<<1040, 256, 0, stream>>>(style, fc_w, fc_b, m, conv_w, q, WbU, guard);
    k_prep2<<<1280, 256, 0, stream>>>(x, m, XtU, q, dmod);
    k_gemm<<<dim3(2, 4, 32), 512, 0, stream>>>(XtU, WbU, dmod, bias, noise, out, guard);
}

// Round 5
// 182.240 us; speedup vs baseline: 1.2433x; 1.1083x over previous
//
#include <hip/hip_runtime.h>

typedef short v8s __attribute__((ext_vector_type(8)));
typedef float f32x4 __attribute__((ext_vector_type(4)));
typedef unsigned short ushort_t;

#define BB    8
#define CIN   512
#define COUT  512
#define SDIM  512

// async global->LDS DMA, 16B per lane (wave-uniform LDS base + lane*16)
#define GLDS(g, l)                                                      \
    __builtin_amdgcn_global_load_lds(                                   \
        (const __attribute__((address_space(1))) void*)(g),             \
        (__attribute__((address_space(3))) void*)(l), 16, 0, 0)

static __device__ __forceinline__ ushort_t f2bf(float f) {
    union { float f; unsigned u; } un; un.f = f;
    unsigned r = un.u + 0x7FFF + ((un.u >> 16) & 1);  // round-to-nearest-even
    return (ushort_t)(r >> 16);
}

// ---------------------------------------------------------------------------
// k_prep1: fused  (role by blockIdx)
//   blocks [0,1024):  q[o,c] = sum w^2 ; Wb phase-combined bf16 weights
//   blocks [1024,1040): m[b,c] = 1 + style[b,:] @ fc_w[c,:] + fc_b[c]
//   block 1024 also zeroes the 32B OOB guard used by k_gemm's DMA staging.
// ---------------------------------------------------------------------------
__global__ void k_prep1(const float* __restrict__ style, const float* __restrict__ fc_w,
                        const float* __restrict__ fc_b, float* __restrict__ m,
                        const float* __restrict__ conv_w, float* __restrict__ q,
                        ushort_t* __restrict__ Wb, float* __restrict__ guard) {
    __shared__ float sst[SDIM];
    const int bid = blockIdx.x;
    if (bid < 1024) {
        // ---- wprep role ----
        const int idx = bid * 256 + threadIdx.x;  // o*512 + c
        const int o = idx >> 9, c = idx & 511;
        float w[3][3];
        const float* wp = conv_w + idx * 9;
        float qs = 0.f;
        for (int i = 0; i < 3; i++)
            for (int j = 0; j < 3; j++) {
                float v = wp[i * 3 + j];
                w[i][j] = v;
                qs += v * v;
            }
        q[idx] = qs;
        const int ch = c >> 5, kg = (c >> 3) & 3, c8 = c & 7;
        for (int py = 0; py < 2; py++) {
            float rs[2][3];
            for (int kx = 0; kx < 3; kx++) {
                rs[0][kx] = (py == 0) ? w[0][kx] : w[0][kx] + w[1][kx];
                rs[1][kx] = (py == 0) ? w[1][kx] + w[2][kx] : w[2][kx];
            }
            for (int px = 0; px < 2; px++) {
                const int p = py * 2 + px;
                float vals[4];
                if (px == 0) {
                    vals[0] = rs[0][0];
                    vals[1] = rs[0][1] + rs[0][2];
                    vals[2] = rs[1][0];
                    vals[3] = rs[1][1] + rs[1][2];
                } else {
                    vals[0] = rs[0][0] + rs[0][1];
                    vals[1] = rs[0][2];
                    vals[2] = rs[1][0] + rs[1][1];
                    vals[3] = rs[1][2];
                }
                for (int t = 0; t < 4; t++)
                    Wb[(size_t)p * (16 * 4 * 4 * 512 * 8) + (size_t)ch * (4 * 4 * 512 * 8)
                       + ((size_t)(t * 4 + kg) * 512 + o) * 8 + c8] = f2bf(vals[t]);
            }
        }
    } else {
        // ---- style role ----
        const int sb = bid - 1024;
        const int bx = sb & 1, b = sb >> 1;
        if (sb == 0 && threadIdx.x < 8) guard[threadIdx.x] = 0.f;
        for (int k = threadIdx.x; k < SDIM; k += 256) sst[k] = style[b * SDIM + k];
        __syncthreads();
        const int c = bx * 256 + threadIdx.x;
        float acc = fc_b[c];
        const float* wr = fc_w + c * SDIM;
        for (int k = 0; k < SDIM; k += 4) {
            float4 w4 = *(const float4*)(wr + k);
            acc += w4.x * sst[k] + w4.y * sst[k + 1] + w4.z * sst[k + 2] + w4.w * sst[k + 3];
        }
        m[b * CIN + c] = acc + 1.0f;
    }
}

// ---------------------------------------------------------------------------
// k_prep2: fused  (role by blockIdx)
//   blocks [0,256):    Xt[b][c>>3][r*32+q][c&7] = bf16( x[b][c][r][q]*m[b][c] )
//     (channel-GROUPED layout: k_gemm's X staging reads granule (pix, c-group)
//      -> consecutive pixels are 16B-contiguous, fixing the 4x L2 over-read
//      of the old [pix][c] layout where 16B granules sat at 1KB stride)
//   blocks [256,1280): d[b,o] = rsqrt( sum_c m^2 q + 1e-8 ), one wave/(b,o)
// ---------------------------------------------------------------------------
__global__ void k_prep2(const float* __restrict__ x, const float* __restrict__ m,
                        ushort_t* __restrict__ Xt, const float* __restrict__ q,
                        float* __restrict__ d) {
    __shared__ __align__(16) ushort_t lt[32 * 528];  // [q][c], c-stride 528
    const int bid = blockIdx.x, t = threadIdx.x;
    if (bid < 256) {
        // ---- xprep role ----
        const int r = bid & 31, b = bid >> 5;
        for (int s = t; s < 4096; s += 256) {  // (c, q-quad)
            const int c = s >> 3, q4 = (s & 7) * 4;
            float4 v = *(const float4*)(x + (((size_t)(b * CIN + c) * 32 + r) * 32 + q4));
            const float mv = m[b * CIN + c];
            lt[(q4 + 0) * 528 + c] = f2bf(v.x * mv);
            lt[(q4 + 1) * 528 + c] = f2bf(v.y * mv);
            lt[(q4 + 2) * 528 + c] = f2bf(v.z * mv);
            lt[(q4 + 3) * 528 + c] = f2bf(v.w * mv);
        }
        __syncthreads();
        for (int s = t; s < 2048; s += 256) {  // (c-group, q)
            const int cg = s >> 5, qq = s & 31;
            v8s v = *(v8s*)&lt[qq * 528 + cg * 8];
            *(v8s*)(Xt + (((size_t)(b * 64 + cg) * 1024) + r * 32 + qq) * 8) = v;
        }
    } else {
        // ---- demod role ----
        const int w = (bid - 256) * 4 + (t >> 6);  // 0..4095
        const int L = t & 63;
        const int b = w >> 9, o = w & 511;
        float4 q1 = *(const float4*)(q + o * 512 + L * 8);
        float4 q2 = *(const float4*)(q + o * 512 + L * 8 + 4);
        float4 m1 = *(const float4*)(m + b * 512 + L * 8);
        float4 m2 = *(const float4*)(m + b * 512 + L * 8 + 4);
        float acc = m1.x * m1.x * q1.x + m1.y * m1.y * q1.y + m1.z * m1.z * q1.z +
                    m1.w * m1.w * q1.w + m2.x * m2.x * q2.x + m2.y * m2.y * q2.y +
                    m2.z * m2.z * q2.z + m2.w * m2.w * q2.w;
        for (int off = 32; off; off >>= 1) acc += __shfl_down(acc, off, 64);
        if (L == 0) d[w] = rsqrtf(acc + 1e-8f);
    }
}

// ---------------------------------------------------------------------------
// k_gemm v6: ONE barrier per K-tile (v5 had 4 -> 3630 cy/tile vs ~1250 cy of
// pipe work; barrier rendezvous at 1 block/CU was the dominant dead time).
// Per tile: {12 ds_read issue | 4 GLDS stage(t+3) | 32 MFMA with
// compiler-counted lgkm waits (quad0 starts when its 8 reads land, quad1's
// reads served under quad0's MFMAs) | vmcnt(4) | s_barrier}.
// Ring-4 K-tile LDS (4x32KB=128KB) makes the single barrier race-free:
// stage(t+3) overwrites the buffer whose reads were consumed in tile t-1,
// strictly before the end-of-(t-1) barrier. Counted vmcnt pre-barrier,
// never 0 until the tail taper. Staging/read index math + swizzle verbatim
// v5 (measured zero bank conflicts). X source now channel-grouped ->
// contiguous 256B runs (was 16B @ 1KB stride).
// ---------------------------------------------------------------------------
__global__ __launch_bounds__(512, 2) void k_gemm(
    const ushort_t* __restrict__ Xt, const ushort_t* __restrict__ Wb,
    const float* __restrict__ dmod, const float* __restrict__ bias,
    const float* __restrict__ noise, float* __restrict__ out,
    const float* __restrict__ guard) {
    __shared__ __align__(16) ushort_t Wt[4][256 * 32];  // [o-local][k], swizzled
    __shared__ __align__(16) ushort_t Xs[4][256 * 32];  // [n-local][k], swizzled

    const int tid = threadIdx.x;
    const int L = tid & 63;

    // bijective chunked XCD swizzle: 256 blocks, XCD k owns logical [k*32,(k+1)*32)
    const int lin = blockIdx.x + 2 * blockIdx.y + 8 * blockIdx.z;
    const int log = (lin & 7) * 32 + (lin >> 3);
    const int o0 = (log & 1) * 256;
    const int n0 = ((log >> 1) & 3) * 256;
    const int zz = log >> 3;
    const int b = zz >> 2, p = zz & 3;

    const int wid = tid >> 6;
    const int py = p >> 1, px = p & 1;
    const int ry0 = py ? 0 : -1, cx0 = px ? 0 : -1;
    const int wo = (wid >> 2) * 128, wn = (wid & 3) * 64;
    const int l15 = L & 15, l4 = L >> 4;

    const ushort_t* XtB = Xt + (size_t)b * (64 * 1024 * 8);  // [cg][pix][8]
    const ushort_t* WbP = Wb + (size_t)p * (16 * 4 * 4 * 512 * 8);

    f32x4 acc[8][4];
#pragma unroll
    for (int i = 0; i < 8; i++)
#pragma unroll
        for (int j = 0; j < 4; j++) acc[i][j] = {0.f, 0.f, 0.f, 0.f};

    // ---- staging: one op = 512 lanes x 16B = 8KB = half a 16KB tile ----
    // LDS slot s (16B units): row = s>>2, stored granule gs = s&3,
    // logical tap = gs ^ ((row>>1)&3). Channels c0..c0+7 (BK=32).
    auto stage1 = [&](int c0, ushort_t* wbuf, ushort_t* xbuf, int i) {
        const int slot = i * 512 + tid;
        const int row = slot >> 2;
        const int tap = (slot & 3) ^ ((row >> 1) & 3);
        const int ldo = (i * 512 + (tid & 448)) * 8;  // wave-uniform base
        const ushort_t* wsrc =
            WbP + (size_t)(c0 >> 5) * (4 * 4 * 512 * 8)
            + ((size_t)((tap * 4 + ((c0 >> 3) & 3)) * 512 + o0 + row)) * 8;
        GLDS(wsrc, wbuf + ldo);
        const int pix = n0 + row;
        const int gr = (pix >> 5) + ry0 + (tap >> 1);
        const int gq = (pix & 31) + cx0 + (tap & 1);
        const ushort_t* xsrc =
            ((unsigned)gr < 32u && (unsigned)gq < 32u)
                ? XtB + ((size_t)(c0 >> 3) * 1024 + gr * 32 + gq) * 8
                : (const ushort_t*)guard;
        GLDS(xsrc, xbuf + ldo);
    };

    // fragment read: row in [0,256), k-granule l4, swizzled
    auto lread = [&](const ushort_t* buf, int row) -> v8s {
        const int gsel = l4 ^ ((row >> 1) & 3);
        return *(const v8s*)&buf[row * 32 + gsel * 8];
    };

    // ---- prologue: stage tiles 0,1,2 (12 ops); wait tile0 (vmcnt(8)) ----
#pragma unroll
    for (int pt = 0; pt < 3; ++pt) {
        stage1(pt * 8, Wt[pt], Xs[pt], 0);
        stage1(pt * 8, Wt[pt], Xs[pt], 1);
    }
    asm volatile("s_waitcnt vmcnt(8)" ::: "memory");
    __builtin_amdgcn_s_barrier();

    for (int t = 0; t < 64; ++t) {
        const ushort_t* wb = Wt[t & 3];
        const ushort_t* xb = Xs[t & 3];
        ushort_t* wnb = Wt[(t + 3) & 3];
        ushort_t* xnb = Xs[(t + 3) & 3];
        const int c0n = (t + 3) * 8;

        // 1. issue all 12 fragment reads (compiler emits counted lgkm waits:
        //    quad0's MFMAs wait only their 8; quad1's 4 reads are served
        //    underneath quad0's MFMA execution)
        v8s af0[4], af1[4], bfr[4];
#pragma unroll
        for (int i = 0; i < 4; i++) af0[i] = lread(wb, wo + i * 16 + l15);
#pragma unroll
        for (int j = 0; j < 4; j++) bfr[j] = lread(xb, wn + j * 16 + l15);
#pragma unroll
        for (int i = 0; i < 4; i++) af1[i] = lread(wb, wo + 64 + i * 16 + l15);

        // 2. stage tile t+3 into the ring (safe: its buffer's reads were
        //    consumed in tile t-1, before the end-of-(t-1) barrier)
        if (t + 3 < 64) {
            stage1(c0n, wnb, xnb, 0);
            stage1(c0n, wnb, xnb, 1);
        }

        // 3. MFMA: 32 per wave (both o-quadrants, bfr shared)
        __builtin_amdgcn_s_setprio(1);
#pragma unroll
        for (int i = 0; i < 4; i++)
#pragma unroll
            for (int j = 0; j < 4; j++)
                acc[i][j] = __builtin_amdgcn_mfma_f32_16x16x32_bf16(
                    af0[i], bfr[j], acc[i][j], 0, 0, 0);
#pragma unroll
        for (int i = 0; i < 4; i++)
#pragma unroll
            for (int j = 0; j < 4; j++)
                acc[4 + i][j] = __builtin_amdgcn_mfma_f32_16x16x32_bf16(
                    af1[i], bfr[j], acc[4 + i][j], 0, 0, 0);
        __builtin_amdgcn_s_setprio(0);

        // 4. counted vmcnt BEFORE the barrier: confirm tile t+2 staged
        //    (leave t+3's 4 ops in flight); taper only at the tail
        if (t <= 61) asm volatile("s_waitcnt vmcnt(4)" ::: "memory");
        else if (t == 62) asm volatile("s_waitcnt vmcnt(0)" ::: "memory");

        // 5. single block-wide rendezvous per K-tile
        __builtin_amdgcn_s_barrier();
    }

    // ---- epilogue: demod * acc + bias + noise, leaky relu (v3-verified) ----
    const float* db = dmod + b * COUT;
    float nz[4];
    int ooff[4];
#pragma unroll
    for (int j = 0; j < 4; j++) {
        const int pix = n0 + wn + j * 16 + l15;
        const int Y = 2 * (pix >> 5) + py, X = 2 * (pix & 31) + px;
        nz[j] = noise[b * 4096 + Y * 64 + X];
        ooff[j] = Y * 64 + X;
    }
    float* outB = out + (size_t)b * COUT * 4096;
#pragma unroll
    for (int i = 0; i < 8; i++) {
        const int ob = o0 + wo + i * 16 + l4 * 4;
        float4 d4 = *(const float4*)(db + ob);
        float4 b4 = *(const float4*)(bias + ob);
        const float dv[4] = {d4.x, d4.y, d4.z, d4.w};
        const float bv[4] = {b4.x, b4.y, b4.z, b4.w};
#pragma unroll
        for (int reg = 0; reg < 4; reg++) {
            float* orow = outB + (size_t)(ob + reg) * 4096;
#pragma unroll
            for (int j = 0; j < 4; j++) {
                float v = acc[i][j][reg] * dv[reg] + bv[reg] + nz[j];
                orow[ooff[j]] = v > 0.f ? v : 0.2f * v;
            }
        }
    }
}

// ---------------------------------------------------------------------------
extern "C" void kernel_launch(void* const* d_in, const int* in_sizes, int n_in,
                              void* d_out, int out_size, void* d_ws, size_t ws_size,
                              hipStream_t stream) {
    const float* x      = (const float*)d_in[0];
    const float* style  = (const float*)d_in[1];
    const float* noise  = (const float*)d_in[2];
    const float* conv_w = (const float*)d_in[3];
    const float* fc_w   = (const float*)d_in[4];
    const float* fc_b   = (const float*)d_in[5];
    const float* bias   = (const float*)d_in[6];
    float* out = (float*)d_out;

    float* ws = (float*)d_ws;
    float* m     = ws;             // 8*512 floats
    float* dmod  = ws + 4096;      // 8*512
    float* q     = ws + 8192;      // 512*512
    float* guard = ws + 270336;    // 8 floats (32B zero guard, 16B-aligned)
    ushort_t* XtU = (ushort_t*)(ws + 270352);  // 8*64*1024*8 bf16 (c-grouped)
    ushort_t* WbU = XtU + 4194304;             // 4*16*4*4*512*8 bf16

    k_prep1<<<1040, 256, 0, stream>>>(style, fc_w, fc_b, m, conv_w, q, WbU, guard);
    k_prep2<<<1280, 256, 0, stream>>>(x, m, XtU, q, dmod);
    k_gemm<<<dim3(2, 4, 32), 512, 0, stream>>>(XtU, WbU, dmod, bias, noise, out, guard);
}